// Round 12
// baseline (288.911 us; speedup 1.0000x reference)
//
#include <hip/hip_runtime.h>

// Caps_BN: BatchNorm2d (training stats, affine=False) + grouped 1x1 conv
// (16 capsules of 32x32) + bias. x (64, 512, 32, 32) f32.
//
// SINGLE fused kernel, per-capsule producer->consumer sync (no grid barrier):
//   blocks 0..511   : stats for channel ch=b -> fold W' column + b' atomic
//                     contribution -> release-add cnt[capsule].
//   blocks 512..4607: spin on ATOMIC LOAD (no RMW polling -- R9's 500us lesson)
//                     of cnt[c], then run the R5-proven main body (s_load W'/b'
//                     from ws; NO LDS in the hot path).
//
// R11 lesson (VGPR=32, 307us): adding LDS-broadcast normalize inside the main
// body made the allocator spill xv[32] to scratch (L2-absorbed, invisible in
// HBM counters -- same signature as R6). R9 proved {stats-LDS branch + spin +
// s_load main body} compiles clean at VGPR 52. So the fold is done by the
// stats blocks and main stays byte-identical to R5's proven caps_main.
//
// ws layout (floats):
//   [0, 512)        mean (unused downstream, kept for debug)
//   [512, 1024)     rstd (unused downstream)
//   [1024, 17408)   W' folded weight (c, o, i)
//   [17408, 17920)  b' folded bias (c, o)   -- seeded with bias by bar_init,
//                                              stats blocks atomicAdd -W'*mean
//   [17920, 17936)  cnt[16] capsule arrival counters (ints)
//
// Other encoded lessons:
//  - R8: cooperative grid.sync is not graph-capture-safe.
//  - NEVER set launch_bounds min-waves (R4/R6: forced VGPR=40 + spills).
//  - xv[32] + 4 independent partials = proven spill-free ILP shape (R5).
//  - scalar 4B/lane loads/stores = exactly 1.0x WRITE_SIZE; nt stores keep
//    out from evicting L3-resident x (R6/R9/R11: FETCH == one x read).
//  - bar_init re-seeds b' and counters EVERY launch -> graph replays identical.

#define NELEM_PER_CH 65536.0f
#define WS_WP   1024
#define WS_BP   17408
#define WS_CNT  17920

__global__ void bar_init(const float* __restrict__ bias,
                         float* __restrict__ ws, int* __restrict__ cnt) {
    const int t = threadIdx.x;          // 512 threads
    ws[WS_BP + t] = bias[t];            // seed b' with bias
    if (t < 16) cnt[t] = 0;
}

__global__ __launch_bounds__(256) void caps_fused(const float* __restrict__ x,
                                                  const float* __restrict__ w,
                                                  float* __restrict__ out,
                                                  float* __restrict__ ws,
                                                  int* __restrict__ cnt) {
    const int b = blockIdx.x;
    const int t = threadIdx.x;

    if (b < 512) {
        // ---- stats + fold-column block: channel ch = b ----
        const int ch = b;
        const int c  = ch >> 5;
        const int i  = ch & 31;
        const float4* __restrict__ x4 = (const float4*)x;
        float s = 0.f, ss = 0.f;
#pragma unroll 4
        for (int n = 0; n < 64; ++n) {
            float4 v = x4[((size_t)n * 512 + ch) * 256 + t];
            s  += v.x + v.y + v.z + v.w;
            ss += v.x * v.x + v.y * v.y + v.z * v.z + v.w * v.w;
        }
#pragma unroll
        for (int off = 32; off > 0; off >>= 1) {
            s  += __shfl_down(s, off);
            ss += __shfl_down(ss, off);
        }
        __shared__ float red[4][2];
        __shared__ float sm, sr;
        if ((t & 63) == 0) { red[t >> 6][0] = s; red[t >> 6][1] = ss; }
        __syncthreads();
        if (t == 0) {
            float S = 0.f, SS = 0.f;
#pragma unroll
            for (int k = 0; k < 4; ++k) { S += red[k][0]; SS += red[k][1]; }
            const float mean = S / NELEM_PER_CH;
            const float rstd = rsqrtf(SS / NELEM_PER_CH - mean * mean + 1e-5f);
            ws[ch] = mean;
            ws[512 + ch] = rstd;
            sm = mean; sr = rstd;
        }
        __syncthreads();
        if (t < 32) {
            const int o = t;
            const float wv = w[c * 1024 + o * 32 + i] * sr;   // W'[o][i]
            ws[WS_WP + c * 1024 + o * 32 + i] = wv;
            atomicAdd(&ws[WS_BP + c * 32 + o], -wv * sm);     // b' -= W'*mean
        }
        __syncthreads();              // drain the 32 atomics + W' stores (vmcnt)
        __threadfence();              // make them visible device-wide
        if (t == 0)
            __hip_atomic_fetch_add(&cnt[c], 1, __ATOMIC_RELEASE,
                                   __HIP_MEMORY_SCOPE_AGENT);
        return;
    }

    // ---- main block: tile m = b - 512; same (q,c,n) order as R5 ----
    const int m = b - 512;            // 0..4095
    const int q = m & 3;
    const int c = (m >> 2) & 15;
    const int n = m >> 6;

    // wait until this capsule's 32 channel-columns are folded (read-only polls)
    if (t == 0) {
        int spins = 0;
        while (__hip_atomic_load(&cnt[c], __ATOMIC_ACQUIRE,
                                 __HIP_MEMORY_SCOPE_AGENT) < 32 &&
               spins < (1 << 20)) {
            ++spins;
            __builtin_amdgcn_s_sleep(8);
        }
    }
    __syncthreads();

    const int hw = q * 256 + t;
    const size_t base = (((size_t)n * 16 + c) * 32) * 1024 + hw;
    const float* __restrict__ Wc = ws + WS_WP + c * 1024;   // block-uniform
    const float* __restrict__ b2 = ws + WS_BP + c * 32;

    float xv[32];
#pragma unroll
    for (int i = 0; i < 32; ++i) xv[i] = x[base + (size_t)i * 1024];

#pragma unroll 4
    for (int o = 0; o < 32; ++o) {
        const float* __restrict__ wr = Wc + o * 32;          // s_load rows
        float p0 = 0.f, p1 = 0.f, p2 = 0.f, p3 = 0.f;
#pragma unroll
        for (int i = 0; i < 32; i += 4) {
            p0 += wr[i + 0] * xv[i + 0];
            p1 += wr[i + 1] * xv[i + 1];
            p2 += wr[i + 2] * xv[i + 2];
            p3 += wr[i + 3] * xv[i + 3];
        }
        __builtin_nontemporal_store(b2[o] + ((p0 + p1) + (p2 + p3)),
                                    out + base + (size_t)o * 1024);
    }
}

extern "C" void kernel_launch(void* const* d_in, const int* in_sizes, int n_in,
                              void* d_out, int out_size, void* d_ws, size_t ws_size,
                              hipStream_t stream) {
    const float* x    = (const float*)d_in[0];
    const float* w    = (const float*)d_in[1];
    const float* bias = (const float*)d_in[2];
    float* out = (float*)d_out;
    float* ws  = (float*)d_ws;
    int* cnt   = (int*)(ws + WS_CNT);

    bar_init<<<1, 512, 0, stream>>>(bias, ws, cnt);
    caps_fused<<<512 + 4096, 256, 0, stream>>>(x, w, out, ws, cnt);
}

// Round 13
// 76.477 us; speedup vs baseline: 3.7778x; 3.7778x over previous
//
#include <hip/hip_runtime.h>

// Caps_BN: BatchNorm2d (training stats, affine=False) + grouped 1x1 conv
// (16 capsules of 32x32) + bias, folded: out = (W*rstd) @ x + (bias - (W*rstd)@mean).
// x (64, 512, 32, 32) f32.
//
// 3-kernel structure. Fusion is ABANDONED after 7 failed rounds (R6-R12):
//  - R8: cooperative grid.sync not graph-capture-safe (replays race).
//  - R9: atomicAdd-RMW polling = fabric storm (~500us).
//  - R11: LDS-normalize in main body -> allocator spilled xv (VGPR 32, 307us).
//  - R12: agent-scope atomics in-kernel kill the W' s_load scalarization
//    (SGPR 112 -> 32, 298us despite ideal traffic). The ~20us fusion prize is
//    always eaten by sync-induced codegen damage.
//
// ws layout (floats):
//   [0, 512)        mean per channel
//   [512, 1024)     rstd per channel
//   [1024, 17408)   W' folded weight (c, o, i)
//   [17408, 17920)  b' folded bias (c, o)
//
// Proven facts encoded:
//  - NEVER set launch_bounds min-waves: (256,6) forced VGPR=40 + scratch spill
//    (R4 113us, R6 440us). Plain (256) compiles this body clean.
//  - xv-major (x arrays + streamed per-o partials) compiles clean (R5, VGPR 52);
//    acc-major arrays spill (R2/R3). This kernel = R5 shape x2 columns.
//  - 4-independent-partial dot products (R5) fix the dependent-chain stall (R1).
//  - scalar 4B/lane loads/stores = the only pattern measured at exactly 1.0x
//    WRITE_SIZE; nt stores keep out from evicting L3-resident x.
//  - stats is at the HBM floor (~21us @ 6.4 TB/s); main target ~35us.

#define NELEM_PER_CH 65536.0f
#define WS_WP   1024
#define WS_BP   17408

__global__ __launch_bounds__(256) void caps_stats(const float* __restrict__ x,
                                                  float* __restrict__ ws) {
    const int ch = blockIdx.x;      // 0..511
    const int tid = threadIdx.x;    // 0..255
    const float4* __restrict__ x4 = (const float4*)x;

    float s = 0.f, ss = 0.f;
#pragma unroll 4
    for (int n = 0; n < 64; ++n) {
        float4 v = x4[((size_t)n * 512 + ch) * 256 + tid];
        s  += v.x + v.y + v.z + v.w;
        ss += v.x * v.x + v.y * v.y + v.z * v.z + v.w * v.w;
    }
#pragma unroll
    for (int off = 32; off > 0; off >>= 1) {
        s  += __shfl_down(s, off);
        ss += __shfl_down(ss, off);
    }
    __shared__ float red[4][2];
    if ((tid & 63) == 0) { red[tid >> 6][0] = s; red[tid >> 6][1] = ss; }
    __syncthreads();
    if (tid == 0) {
        float S = 0.f, SS = 0.f;
#pragma unroll
        for (int k = 0; k < 4; ++k) { S += red[k][0]; SS += red[k][1]; }
        float mean = S / NELEM_PER_CH;
        float var = SS / NELEM_PER_CH - mean * mean;
        ws[ch] = mean;
        ws[512 + ch] = rsqrtf(var + 1e-5f);
    }
}

__global__ __launch_bounds__(1024) void caps_fold(const float* __restrict__ w,
                                                  const float* __restrict__ bias,
                                                  float* __restrict__ ws) {
    const int c = blockIdx.x;
    const int t = threadIdx.x;
    const int o = t >> 5;
    const int i = t & 31;
    const float mean = ws[c * 32 + i];
    const float rstd = ws[512 + c * 32 + i];
    const float wv = w[c * 1024 + t] * rstd;
    ws[WS_WP + c * 1024 + t] = wv;           // W'[c][o][i]
    float prod = wv * mean;
#pragma unroll
    for (int off = 16; off > 0; off >>= 1) prod += __shfl_xor(prod, off);
    if (i == 0) ws[WS_BP + c * 32 + o] = bias[c * 32 + o] - prod;
}

// Main: 2 scalar hw-columns per thread (hw, hw+512), xv-major proven shape x2.
// grid (2, 16, 64) = (hw-half, c, n); block 256. Each s_load W-row feeds both
// columns; 8 independent partials per o keep the FMA stream dependency-free.
__global__ __launch_bounds__(256) void caps_main(const float* __restrict__ x,
                                                 const float* __restrict__ ws,
                                                 float* __restrict__ out) {
    const int c = blockIdx.y;
    const int n = blockIdx.z;
    const int t = threadIdx.x;                         // 0..255
    const int hw0 = blockIdx.x * 256 + t;              // col A: 0..511

    const size_t tile = (((size_t)n * 16 + c) * 32) * 1024;
    const float* __restrict__ xa = x + tile + hw0;     // col A, i-stride 1024
    const float* __restrict__ xb = xa + 512;           // col B
    float* __restrict__ oa = out + tile + hw0;
    float* __restrict__ ob = oa + 512;

    const float* __restrict__ Wc = ws + WS_WP + c * 1024;   // block-uniform
    const float* __restrict__ bp = ws + WS_BP + c * 32;

    float xva[32], xvb[32];
#pragma unroll
    for (int i = 0; i < 32; ++i) xva[i] = xa[(size_t)i * 1024];
#pragma unroll
    for (int i = 0; i < 32; ++i) xvb[i] = xb[(size_t)i * 1024];

#pragma unroll 2
    for (int o = 0; o < 32; ++o) {
        const float* __restrict__ wr = Wc + o * 32;    // s_load row, used twice
        float a0 = 0.f, a1 = 0.f, a2 = 0.f, a3 = 0.f;
        float c0 = 0.f, c1 = 0.f, c2 = 0.f, c3 = 0.f;
#pragma unroll
        for (int i = 0; i < 32; i += 4) {
            const float w0 = wr[i + 0], w1 = wr[i + 1];
            const float w2 = wr[i + 2], w3 = wr[i + 3];
            a0 += w0 * xva[i + 0];  c0 += w0 * xvb[i + 0];
            a1 += w1 * xva[i + 1];  c1 += w1 * xvb[i + 1];
            a2 += w2 * xva[i + 2];  c2 += w2 * xvb[i + 2];
            a3 += w3 * xva[i + 3];  c3 += w3 * xvb[i + 3];
        }
        const float bb = bp[o];
        __builtin_nontemporal_store(bb + ((a0 + a1) + (a2 + a3)),
                                    oa + (size_t)o * 1024);
        __builtin_nontemporal_store(bb + ((c0 + c1) + (c2 + c3)),
                                    ob + (size_t)o * 1024);
    }
}

extern "C" void kernel_launch(void* const* d_in, const int* in_sizes, int n_in,
                              void* d_out, int out_size, void* d_ws, size_t ws_size,
                              hipStream_t stream) {
    const float* x    = (const float*)d_in[0];
    const float* w    = (const float*)d_in[1];
    const float* bias = (const float*)d_in[2];
    float* out = (float*)d_out;
    float* ws  = (float*)d_ws;

    caps_stats<<<512, 256, 0, stream>>>(x, ws);
    caps_fold<<<16, 1024, 0, stream>>>(w, bias, ws);
    caps_main<<<dim3(2, 16, 64), 256, 0, stream>>>(x, ws, out);
}